// Round 5
// baseline (56.678 us; speedup 1.0000x reference)
//
#include <hip/hip_runtime.h>
#include <math.h>

// x: [32,3,512,512] f32.
// Shuffle-free register row sweep: each lane owns 8 columns and loads a
// 2-column halo on each side (12 floats/row), so Sobel (10 cols) and the
// 3x3 avg pool (8 cols) are computed entirely lane-locally.
// Sobel separable: a = vert[1,2,1], b = vert[1,0,-1];
//   gx = a[k]-a[k+2], gy = b[k]+2b[k+1]+b[k+2]  (k = col-1 offset)
// Pool: zero-pad, /9 always (count_include_pad).
// Grid: (16, 96) x 256 threads -> 96 (b,c) * 64 waves, 8 output rows/wave.

__global__ __launch_bounds__(256, 4) void sobel_pool_stats(
    const float* __restrict__ x, double* __restrict__ parts) {
  const int tid = threadIdx.x;
  const int lane = tid & 63;
  const int wib = tid >> 6;
  const int bc = blockIdx.y;                 // 0..95
  const int wloc = blockIdx.x * 4 + wib;     // 0..63
  const int row0 = wloc * 8;

  const float* __restrict__ xb = x + (size_t)bc * (512 * 512);
  const int c0 = lane * 8;
  const int cl = (lane > 0) ? c0 - 2 : 0;     // 8B-aligned, in-bounds
  const int cr = (lane < 63) ? c0 + 8 : 504;  // 8B-aligned, in-bounds
  const float lmask = (lane > 0) ? 1.f : 0.f;
  const float rmask = (lane < 63) ? 1.f : 0.f;

  float xA[12], xB[12], xC[12];
  float MM[10], MC[10], MP[10];

  // load x[r][c0-2 .. c0+9]; zeros outside the image
  auto load12 = [&](int r, float* o) {
    if ((unsigned)r < 512u) {
      const float* row = xb + (size_t)r * 512;
      float4 u = *(const float4*)(row + c0);
      float4 v = *(const float4*)(row + c0 + 4);
      float2 lw = *(const float2*)(row + cl);
      float2 rw = *(const float2*)(row + cr);
      o[0] = lw.x * lmask; o[1] = lw.y * lmask;
      o[2] = u.x; o[3] = u.y; o[4] = u.z; o[5] = u.w;
      o[6] = v.x; o[7] = v.y; o[8] = v.z; o[9] = v.w;
      o[10] = rw.x * rmask; o[11] = rw.y * rmask;
    } else {
#pragma unroll
      for (int j = 0; j < 12; ++j) o[j] = 0.f;
    }
  };

  // Sobel magnitude for mag-row mr, columns c0-1 .. c0+8 (k=0..9);
  // 0 for OOB rows/cols (pool zero-padding).
  auto mag10 = [&](const float* xm, const float* x0, const float* xp,
                   int mr, float* mg) {
    if ((unsigned)mr >= 512u) {   // uniform branch (mr same across wave)
#pragma unroll
      for (int k = 0; k < 10; ++k) mg[k] = 0.f;
      return;
    }
    float a[12], b[12];
#pragma unroll
    for (int j = 0; j < 12; ++j) {
      a[j] = (xm[j] + xp[j]) + 2.f * x0[j];   // vertical [1,2,1]
      b[j] = xm[j] - xp[j];                   // vertical [1,0,-1]
    }
#pragma unroll
    for (int k = 0; k < 10; ++k) {
      float gx = a[k] - a[k + 2];                     // horiz [1,0,-1]
      float gy = (b[k] + b[k + 2]) + 2.f * b[k + 1];  // horiz [1,2,1]
      mg[k] = sqrtf(gx * gx + gy * gy + 1e-6f);
    }
    mg[0] *= lmask;   // col -1 (image edge) -> 0 for lane 0
    mg[9] *= rmask;   // col 512 -> 0 for lane 63
  };

  // warmup: mag rows row0-1, row0
  load12(row0 - 2, xA);
  load12(row0 - 1, xB);
  load12(row0, xC);
  mag10(xA, xB, xC, row0 - 1, MM);
#pragma unroll
  for (int j = 0; j < 12; ++j) xA[j] = xB[j];
#pragma unroll
  for (int j = 0; j < 12; ++j) xB[j] = xC[j];
  load12(row0 + 1, xC);
  mag10(xA, xB, xC, row0, MC);

  float s = 0.f, ss = 0.f;

#pragma unroll
  for (int i = 0; i < 8; ++i) {
    const int r = row0 + i;
#pragma unroll
    for (int j = 0; j < 12; ++j) xA[j] = xB[j];
#pragma unroll
    for (int j = 0; j < 12; ++j) xB[j] = xC[j];
    load12(r + 2, xC);
    mag10(xA, xB, xC, r + 1, MP);

    float cs[10];
#pragma unroll
    for (int k = 0; k < 10; ++k) cs[k] = (MM[k] + MP[k]) + MC[k];
#pragma unroll
    for (int j = 0; j < 8; ++j) {
      float pooled = ((cs[j] + cs[j + 2]) + cs[j + 1]) * (1.f / 9.f);
      s += pooled;
      ss += pooled * pooled;
    }
#pragma unroll
    for (int k = 0; k < 10; ++k) MM[k] = MC[k];
#pragma unroll
    for (int k = 0; k < 10; ++k) MC[k] = MP[k];
  }

  // wave reduction in double (exact past this point)
  double ds = (double)s, dss = (double)ss;
  for (int off = 32; off > 0; off >>= 1) {
    ds += __shfl_down(ds, off);
    dss += __shfl_down(dss, off);
  }
  if (lane == 0) {
    size_t idx = ((size_t)bc * 64 + wloc) * 2;
    parts[idx] = ds;
    parts[idx + 1] = dss;
  }
}

// Reduce 64 wave-partials per (b,c), feats [32,6]=[m0,s0,m1,s1,m2,s2], MLP.
__global__ __launch_bounds__(256) void stats_mlp(
    const double* __restrict__ parts,
    const float* __restrict__ w1, const float* __restrict__ b1,
    const float* __restrict__ w2, const float* __restrict__ b2,
    float* __restrict__ out) {
  __shared__ float feats[32 * 6];
  __shared__ float hbuf[32 * 32];
  const int tid = threadIdx.x;

  if (tid < 96) {
    int b = tid / 3;
    int ch = tid - b * 3;
    double s = 0.0, ss = 0.0;
    const double* p = parts + (size_t)tid * 128;  // 64 waves * 2 doubles
#pragma unroll
    for (int t = 0; t < 64; ++t) {
      s += p[2 * t];
      ss += p[2 * t + 1];
    }
    const double N = 262144.0;
    double mean = s / N;
    double var = (ss - s * s / N) / (N - 1.0);
    if (var < 0.0) var = 0.0;
    feats[b * 6 + 2 * ch] = (float)mean;
    feats[b * 6 + 2 * ch + 1] = (float)sqrt(var);
  }
  __syncthreads();

  for (int idx = tid; idx < 32 * 32; idx += 256) {
    int i = idx >> 5, j = idx & 31;
    float acc = b1[j];
#pragma unroll
    for (int k = 0; k < 6; ++k) acc += feats[i * 6 + k] * w1[j * 6 + k];
    hbuf[idx] = acc > 0.f ? acc : 0.f;
  }
  __syncthreads();

  for (int idx = tid; idx < 2048; idx += 256) {
    int i = idx >> 6, o = idx & 63;
    float acc = b2[o];
#pragma unroll
    for (int j = 0; j < 32; ++j) acc += hbuf[i * 32 + j] * w2[o * 32 + j];
    out[idx] = acc;
  }
}

extern "C" void kernel_launch(void* const* d_in, const int* in_sizes, int n_in,
                              void* d_out, int out_size, void* d_ws, size_t ws_size,
                              hipStream_t stream) {
  const float* x = (const float*)d_in[0];
  const float* w1 = (const float*)d_in[1];
  const float* b1 = (const float*)d_in[2];
  const float* w2 = (const float*)d_in[3];
  const float* b2 = (const float*)d_in[4];
  float* out = (float*)d_out;
  double* parts = (double*)d_ws;  // 96*64*2 doubles = 98304 B

  dim3 grid(16, 96);
  sobel_pool_stats<<<grid, 256, 0, stream>>>(x, parts);
  stats_mlp<<<1, 256, 0, stream>>>(parts, w1, b1, w2, b2, out);
}

// Round 6
// 56.608 us; speedup vs baseline: 1.0012x; 1.0012x over previous
//
#include <hip/hip_runtime.h>
#include <math.h>

// x: [32,3,512,512] f32.
// Shuffle-free register row sweep: each lane owns 8 columns + 2-col halo each
// side (12 floats/row), Sobel (10 cols) and 3x3 avg pool (8 cols) fully
// lane-local. Live-across-iteration state minimized to 2 x-rows + 2 mag-rows
// (44 floats) to avoid the r5 spill (VGPR=64 cap -> 38MB scratch writes).
// Grid: (16, 96) x 256 threads -> 96 (b,c) * 64 waves, 8 output rows/wave.

__global__ __launch_bounds__(256) void sobel_pool_stats(
    const float* __restrict__ x, double* __restrict__ parts) {
  const int tid = threadIdx.x;
  const int lane = tid & 63;
  const int wib = tid >> 6;
  const int bc = blockIdx.y;                 // 0..95
  const int wloc = blockIdx.x * 4 + wib;     // 0..63
  const int row0 = wloc * 8;

  const float* __restrict__ xb = x + (size_t)bc * (512 * 512);
  const int c0 = lane * 8;
  const int cl = (lane > 0) ? c0 - 2 : 0;     // 8B-aligned, in-bounds
  const int cr = (lane < 63) ? c0 + 8 : 504;  // 8B-aligned, in-bounds
  const float lmask = (lane > 0) ? 1.f : 0.f;
  const float rmask = (lane < 63) ? 1.f : 0.f;

  // load x[r][c0-2 .. c0+9]; zeros outside the image
  auto load12 = [&](int r, float* o) {
    if ((unsigned)r < 512u) {
      const float* row = xb + (size_t)r * 512;
      float4 u = *(const float4*)(row + c0);
      float4 v = *(const float4*)(row + c0 + 4);
      float2 lw = *(const float2*)(row + cl);
      float2 rw = *(const float2*)(row + cr);
      o[0] = lw.x * lmask; o[1] = lw.y * lmask;
      o[2] = u.x; o[3] = u.y; o[4] = u.z; o[5] = u.w;
      o[6] = v.x; o[7] = v.y; o[8] = v.z; o[9] = v.w;
      o[10] = rw.x * rmask; o[11] = rw.y * rmask;
    } else {
#pragma unroll
      for (int j = 0; j < 12; ++j) o[j] = 0.f;
    }
  };

  // Sobel magnitude for mag-row mr from 3 x-rows; cols c0-1..c0+8 (k=0..9).
  auto mag10 = [&](const float* xm, const float* x0, const float* xp,
                   int mr, float* mg) {
    if ((unsigned)mr >= 512u) {   // uniform branch (mr same across wave)
#pragma unroll
      for (int k = 0; k < 10; ++k) mg[k] = 0.f;
      return;
    }
    float a[12], b[12];
#pragma unroll
    for (int j = 0; j < 12; ++j) {
      a[j] = (xm[j] + xp[j]) + 2.f * x0[j];   // vertical [1,2,1]
      b[j] = xm[j] - xp[j];                   // vertical [1,0,-1]
    }
#pragma unroll
    for (int k = 0; k < 10; ++k) {
      float gx = a[k] - a[k + 2];                     // horiz [1,0,-1]
      float gy = (b[k] + b[k + 2]) + 2.f * b[k + 1];  // horiz [1,2,1]
      mg[k] = sqrtf(gx * gx + gy * gy + 1e-6f);
    }
    mg[0] *= lmask;   // col -1 (image edge) -> 0 for lane 0
    mg[9] *= rmask;   // col 512 -> 0 for lane 63
  };

  // Live-across-iteration state: xp=x[r], xc=x[r+1], MM=mag[r-1], MC=mag[r].
  float xp[12], xc[12];
  float MM[10], MC[10];

  {
    float t0[12], t1[12];
    load12(row0 - 2, t0);
    load12(row0 - 1, t1);
    load12(row0, xp);                 // xp = x[row0]
    mag10(t0, t1, xp, row0 - 1, MM);
    load12(row0 + 1, xc);             // xc = x[row0+1]
    mag10(t1, xp, xc, row0, MC);
  }

  float s = 0.f, ss = 0.f;           // raw sums of cs3 and cs3^2 (scale later)

#pragma unroll
  for (int i = 0; i < 8; ++i) {
    const int r = row0 + i;
    float xn[12];
    load12(r + 2, xn);                // x[r+2]
    float MP[10];
    mag10(xp, xc, xn, r + 1, MP);     // mag[r+1]

    float cs[10];
#pragma unroll
    for (int k = 0; k < 10; ++k) cs[k] = (MM[k] + MP[k]) + MC[k];
#pragma unroll
    for (int j = 0; j < 8; ++j) {
      float t = (cs[j] + cs[j + 2]) + cs[j + 1];
      s += t;
      ss += t * t;
    }
#pragma unroll
    for (int k = 0; k < 10; ++k) { MM[k] = MC[k]; MC[k] = MP[k]; }
#pragma unroll
    for (int j = 0; j < 12; ++j) { xp[j] = xc[j]; xc[j] = xn[j]; }
  }

  // wave reduction in double; fold in the deferred /9 and /81
  double ds = (double)s * (1.0 / 9.0);
  double dss = (double)ss * (1.0 / 81.0);
  for (int off = 32; off > 0; off >>= 1) {
    ds += __shfl_down(ds, off);
    dss += __shfl_down(dss, off);
  }
  if (lane == 0) {
    size_t idx = ((size_t)bc * 64 + wloc) * 2;
    parts[idx] = ds;
    parts[idx + 1] = dss;
  }
}

// Reduce 64 wave-partials per (b,c), feats [32,6]=[m0,s0,m1,s1,m2,s2], MLP.
__global__ __launch_bounds__(256) void stats_mlp(
    const double* __restrict__ parts,
    const float* __restrict__ w1, const float* __restrict__ b1,
    const float* __restrict__ w2, const float* __restrict__ b2,
    float* __restrict__ out) {
  __shared__ float feats[32 * 6];
  __shared__ float hbuf[32 * 32];
  const int tid = threadIdx.x;

  if (tid < 96) {
    int b = tid / 3;
    int ch = tid - b * 3;
    double s = 0.0, ss = 0.0;
    const double* p = parts + (size_t)tid * 128;  // 64 waves * 2 doubles
#pragma unroll
    for (int t = 0; t < 64; ++t) {
      s += p[2 * t];
      ss += p[2 * t + 1];
    }
    const double N = 262144.0;
    double mean = s / N;
    double var = (ss - s * s / N) / (N - 1.0);
    if (var < 0.0) var = 0.0;
    feats[b * 6 + 2 * ch] = (float)mean;
    feats[b * 6 + 2 * ch + 1] = (float)sqrt(var);
  }
  __syncthreads();

  for (int idx = tid; idx < 32 * 32; idx += 256) {
    int i = idx >> 5, j = idx & 31;
    float acc = b1[j];
#pragma unroll
    for (int k = 0; k < 6; ++k) acc += feats[i * 6 + k] * w1[j * 6 + k];
    hbuf[idx] = acc > 0.f ? acc : 0.f;
  }
  __syncthreads();

  for (int idx = tid; idx < 2048; idx += 256) {
    int i = idx >> 6, o = idx & 63;
    float acc = b2[o];
#pragma unroll
    for (int j = 0; j < 32; ++j) acc += hbuf[i * 32 + j] * w2[o * 32 + j];
    out[idx] = acc;
  }
}

extern "C" void kernel_launch(void* const* d_in, const int* in_sizes, int n_in,
                              void* d_out, int out_size, void* d_ws, size_t ws_size,
                              hipStream_t stream) {
  const float* x = (const float*)d_in[0];
  const float* w1 = (const float*)d_in[1];
  const float* b1 = (const float*)d_in[2];
  const float* w2 = (const float*)d_in[3];
  const float* b2 = (const float*)d_in[4];
  float* out = (float*)d_out;
  double* parts = (double*)d_ws;  // 96*64*2 doubles = 98304 B

  dim3 grid(16, 96);
  sobel_pool_stats<<<grid, 256, 0, stream>>>(x, parts);
  stats_mlp<<<1, 256, 0, stream>>>(parts, w1, b1, w2, b2, out);
}

// Round 7
// 41.387 us; speedup vs baseline: 1.3695x; 1.3678x over previous
//
#include <hip/hip_runtime.h>
#include <math.h>

// x: [32,3,512,512] f32.
// LDS-staged register row sweep. Block = 512 threads (8 waves), covers
// 32 output rows x full 512 width. x rows [r0-2, r0+33] (36 rows, 72KB)
// staged to LDS once (OOB rows zero-filled at staging -> branch-free
// compute). Each wave: 4 output rows; each lane: 8 cols + 2-col halo read
// lane-locally from LDS. Sobel via rolling vertical pair-sums
// (a = S_prev+S_new, b = S_prev-S_new), mag = raw v_sqrt_f32, 3x3 pool
// zero-pad /9 (deferred), f32 partials -> double -> stats+MLP kernel.
// Grid: (16, 96) x 512.

#define RPB 32          // output rows per block
#define XROWS (RPB + 4) // 36 staged x rows

__global__ __launch_bounds__(512) void sobel_pool_stats(
    const float* __restrict__ x, double* __restrict__ parts) {
  __shared__ float sx[XROWS * 512];
  __shared__ double red[16];

  const int tid = threadIdx.x;
  const int lane = tid & 63;
  const int w = tid >> 6;                  // wave 0..7
  const int bc = blockIdx.y;               // 0..95
  const int r0 = blockIdx.x * RPB;
  const float* __restrict__ xb = x + (size_t)bc * (512 * 512);

  // ---- stage x rows [r0-2, r0+33] into LDS; zeros for OOB rows ----
  for (int i = tid; i < XROWS * 128; i += 512) {
    int row = i >> 7;                      // LDS row
    int pos = (i & 127) << 2;              // float offset in row
    int xr = r0 - 2 + row;
    float4 v = make_float4(0.f, 0.f, 0.f, 0.f);
    if ((unsigned)xr < 512u)
      v = *(const float4*)(xb + (size_t)xr * 512 + pos);
    *(float4*)(&sx[row * 512 + pos]) = v;
  }
  __syncthreads();

  // ---- per-lane column window: cols c0-2 .. c0+9 ----
  const int c0 = lane * 8;
  const float lmask = (lane > 0) ? 1.f : 0.f;
  const float rmask = (lane < 63) ? 1.f : 0.f;
  const int dl = (lane > 0) ? (c0 - 2) : 0;    // 8B-aligned
  const int dr = (lane < 63) ? (c0 + 8) : 504; // 8B-aligned

  auto read12 = [&](int j, float* o) {
    const float* base = &sx[j * 512];
    float2 L = *(const float2*)(base + dl);
    float4 u = *(const float4*)(base + c0);
    float4 v = *(const float4*)(base + c0 + 4);
    float2 R = *(const float2*)(base + dr);
    o[0] = L.x * lmask; o[1] = L.y * lmask;
    o[2] = u.x; o[3] = u.y; o[4] = u.z; o[5] = u.w;
    o[6] = v.x; o[7] = v.y; o[8] = v.z; o[9] = v.w;
    o[10] = R.x * rmask; o[11] = R.y * rmask;
  };

  // advance vertical window: S=x[M-1]+x[M], X=x[M]; consume xn=x[M+1];
  // emit mag row M (zero if M outside image), then S,X advance.
  auto magstep = [&](float* S, float* X, const float* xn, int mr, float* mg) {
    float S2[12];
#pragma unroll
    for (int k = 0; k < 12; ++k) S2[k] = X[k] + xn[k];
    if ((unsigned)mr < 512u) {             // uniform per wave
      float a[12], b[12];
#pragma unroll
      for (int k = 0; k < 12; ++k) { a[k] = S[k] + S2[k]; b[k] = S[k] - S2[k]; }
#pragma unroll
      for (int k = 0; k < 10; ++k) {
        float gx = a[k] - a[k + 2];                     // horiz [1,0,-1]
        float gy = (b[k] + b[k + 2]) + 2.f * b[k + 1];  // horiz [1,2,1]
        mg[k] = __builtin_amdgcn_sqrtf(gx * gx + gy * gy + 1e-6f);
      }
      mg[0] *= lmask;   // col -1 of image -> 0
      mg[9] *= rmask;   // col 512 -> 0
    } else {
#pragma unroll
      for (int k = 0; k < 10; ++k) mg[k] = 0.f;
    }
#pragma unroll
    for (int k = 0; k < 12; ++k) { S[k] = S2[k]; X[k] = xn[k]; }
  };

  const int R0 = r0 + w * 4;               // this wave's 4 output rows
  const int j0 = w * 4;                    // LDS row of x row R0-2
  float S[12], X[12], xn[12], MM[10], MC[10];

  {
    float t0[12], t1[12];
    read12(j0, t0);                        // x[R0-2]
    read12(j0 + 1, t1);                    // x[R0-1]
#pragma unroll
    for (int k = 0; k < 12; ++k) { S[k] = t0[k] + t1[k]; X[k] = t1[k]; }
  }
  read12(j0 + 2, xn);                      // x[R0]
  magstep(S, X, xn, R0 - 1, MM);           // mag[R0-1]
  read12(j0 + 3, xn);                      // x[R0+1]
  magstep(S, X, xn, R0, MC);               // mag[R0]

  float s = 0.f, ss = 0.f;
#pragma unroll
  for (int i = 0; i < 4; ++i) {
    read12(j0 + 4 + i, xn);                // x[R0+i+2]
    float MP[10];
    magstep(S, X, xn, R0 + i + 1, MP);     // mag[R0+i+1]
    float cs[10];
#pragma unroll
    for (int k = 0; k < 10; ++k) cs[k] = (MM[k] + MP[k]) + MC[k];
#pragma unroll
    for (int j = 0; j < 8; ++j) {
      float t = (cs[j] + cs[j + 2]) + cs[j + 1];
      s += t;
      ss += t * t;
    }
#pragma unroll
    for (int k = 0; k < 10; ++k) { MM[k] = MC[k]; MC[k] = MP[k]; }
  }

  // wave reduce in double; fold deferred /9, /81
  double ds = (double)s * (1.0 / 9.0);
  double dss = (double)ss * (1.0 / 81.0);
  for (int off = 32; off > 0; off >>= 1) {
    ds += __shfl_down(ds, off);
    dss += __shfl_down(dss, off);
  }
  if (lane == 0) { red[w * 2] = ds; red[w * 2 + 1] = dss; }
  __syncthreads();
  if (tid == 0) {
    double Sb = 0.0, SSb = 0.0;
#pragma unroll
    for (int q = 0; q < 8; ++q) { Sb += red[q * 2]; SSb += red[q * 2 + 1]; }
    size_t idx = ((size_t)bc * 16 + blockIdx.x) * 2;
    parts[idx] = Sb;
    parts[idx + 1] = SSb;
  }
}

// Reduce 16 block-partials per (b,c), feats [32,6]=[m0,s0,m1,s1,m2,s2], MLP.
__global__ __launch_bounds__(256) void stats_mlp(
    const double* __restrict__ parts,
    const float* __restrict__ w1, const float* __restrict__ b1,
    const float* __restrict__ w2, const float* __restrict__ b2,
    float* __restrict__ out) {
  __shared__ float feats[32 * 6];
  __shared__ float hbuf[32 * 32];
  const int tid = threadIdx.x;

  if (tid < 96) {
    int b = tid / 3;
    int ch = tid - b * 3;
    double s = 0.0, ss = 0.0;
    const double* p = parts + (size_t)tid * 32;  // 16 blocks * 2 doubles
#pragma unroll
    for (int t = 0; t < 16; ++t) {
      s += p[2 * t];
      ss += p[2 * t + 1];
    }
    const double N = 262144.0;
    double mean = s / N;
    double var = (ss - s * s / N) / (N - 1.0);
    if (var < 0.0) var = 0.0;
    feats[b * 6 + 2 * ch] = (float)mean;
    feats[b * 6 + 2 * ch + 1] = (float)sqrt(var);
  }
  __syncthreads();

  for (int idx = tid; idx < 32 * 32; idx += 256) {
    int i = idx >> 5, j = idx & 31;
    float acc = b1[j];
#pragma unroll
    for (int k = 0; k < 6; ++k) acc += feats[i * 6 + k] * w1[j * 6 + k];
    hbuf[idx] = acc > 0.f ? acc : 0.f;
  }
  __syncthreads();

  for (int idx = tid; idx < 2048; idx += 256) {
    int i = idx >> 6, o = idx & 63;
    float acc = b2[o];
#pragma unroll
    for (int j = 0; j < 32; ++j) acc += hbuf[i * 32 + j] * w2[o * 32 + j];
    out[idx] = acc;
  }
}

extern "C" void kernel_launch(void* const* d_in, const int* in_sizes, int n_in,
                              void* d_out, int out_size, void* d_ws, size_t ws_size,
                              hipStream_t stream) {
  const float* x = (const float*)d_in[0];
  const float* w1 = (const float*)d_in[1];
  const float* b1 = (const float*)d_in[2];
  const float* w2 = (const float*)d_in[3];
  const float* b2 = (const float*)d_in[4];
  float* out = (float*)d_out;
  double* parts = (double*)d_ws;  // 96*16*2 doubles = 24576 B

  dim3 grid(16, 96);
  sobel_pool_stats<<<grid, 512, 0, stream>>>(x, parts);
  stats_mlp<<<1, 256, 0, stream>>>(parts, w1, b1, w2, b2, out);
}